// Round 9
// baseline (580.969 us; speedup 1.0000x reference)
//
#include <hip/hip_runtime.h>
#include <cstdint>
#include <cstddef>

typedef __bf16 bf16x8 __attribute__((ext_vector_type(8)));
typedef float  f32x16 __attribute__((ext_vector_type(16)));

union U16 { bf16x8 v; uint4 q; };
union U8  { __bf16 h[4]; unsigned long long u; };

typedef __attribute__((address_space(1))) const unsigned char gas_t;
typedef __attribute__((address_space(3))) unsigned char las_t;
__device__ __forceinline__ void async16(const void* g, void* l) {
    __builtin_amdgcn_global_load_lds((gas_t*)g, (las_t*)l, 16, 0, 0);
}

// level helpers (256-pixel tiles): tile counts 40,10,3,1 -> bounds 40,50,53,54
__device__ __forceinline__ int lvl256(int bx) {
    return (bx < 40) ? 0 : (bx < 50) ? 1 : (bx < 53) ? 2 : 3;
}
__device__ __forceinline__ int tbase256(int lv) {
    return (lv == 0) ? 0 : (lv == 1) ? 40 : (lv == 2) ? 50 : 53;
}
__device__ __forceinline__ size_t loffE(int lv) {
    return (lv == 0) ? 0 : (lv == 1) ? 5242880 : (lv == 2) ? 6553600 : 6881280;
}
__device__ __forceinline__ size_t plog_off(int lv) {
    return (lv == 0) ? 0 : (lv == 1) ? 61440 : (lv == 2) ? 76800 : 80640;
}
__device__ __forceinline__ size_t pdel_off(int lv) {
    return (lv == 0) ? 81600 : (lv == 1) ? 327360 : (lv == 2) ? 388800 : 404160;
}
__device__ __forceinline__ size_t olog_off(int lv) {
    return (lv == 0) ? 408000 : (lv == 1) ? 469440 : (lv == 2) ? 484800 : 488640;
}
__device__ __forceinline__ size_t odel_off(int lv) {
    return (lv == 0) ? 489600 : (lv == 1) ? 735360 : (lv == 2) ? 796800 : 812160;
}
__device__ __forceinline__ int soff_l(int lv) {
    return (lv == 0) ? 0 : (lv == 1) ? 20480 : (lv == 2) ? 25600 : 26880;
}

// ---------------- fused prep, grid 3024 --------------------------------------
__global__ __launch_bounds__(256) void prep_all_k(
    const float* f0, const float* f1, const float* f2, const float* f3,
    const float* pc1w, const float* pc2w, const float* oc1w, const float* oc2w,
    const float* __restrict__ rn1w, const float* __restrict__ rn2w,
    const float* __restrict__ olw,
    __bf16* __restrict__ wtap, float* __restrict__ WpT,
    __bf16* __restrict__ Wo16, __bf16* __restrict__ rn216,
    __bf16* __restrict__ olw32,
    unsigned* __restrict__ zrow32, __bf16* __restrict__ x16)
{
    __shared__ float f[2304];
    int bid = blockIdx.x, tid = threadIdx.x;
    if (bid < 1024) {
        int which = bid >> 8, co = bid & 255;
        const float* srcw = (which == 0) ? pc1w : (which == 1) ? pc2w
                          : (which == 2) ? oc1w : oc2w;
        const float* src = srcw + (size_t)co * 2304;
        for (int i = tid; i < 2304; i += 256) f[i] = src[i];
        __syncthreads();
        __bf16* dst = wtap + (size_t)which * 589824;
        int cg = co >> 6, co64 = co & 63;
        for (int u = tid; u < 288; u += 256) {
            int t = u >> 5, rest = u & 31, c16 = rest >> 1, hf = rest & 1;
            int ci0 = c16 * 16 + hf * 8;
            U16 v;
#pragma unroll
            for (int j = 0; j < 8; ++j) v.v[j] = (__bf16)f[(ci0 + j) * 9 + t];
            *(uint4*)&dst[(size_t)t * 65536 + c16 * 4096 + cg * 1024 + hf * 512 + co64 * 8] = v.q;
        }
    } else if (bid < 1280) {
        int d = bid - 1024, c = tid;
        WpT[c * 256 + d] = rn1w[(size_t)d * 512 + 256 + c];
        Wo16[((c >> 4) * 256 + d) * 16 + (c & 15)] = (__bf16)rn1w[(size_t)d * 512 + c];
        rn216[((c >> 4) * 256 + d) * 16 + (c & 15)] = (__bf16)rn2w[(size_t)d * 256 + c];
        if (d == 0) zrow32[c] = 0u;
    } else if (bid < 3008) {
        int u = bid - 1280;
        int bx = u >> 5, rr = u & 31, n = rr >> 4, ch = rr & 15;
        int lv = lvl256(bx);
        int HW = 10240 >> (2 * lv);
        int p = (bx - tbase256(lv)) * 256 + tid;
        if (p >= HW) return;
        const float* fp = (lv == 0) ? f0 : (lv == 1) ? f1 : (lv == 2) ? f2 : f3;
        const float* src = fp + (size_t)n * 256 * HW + (size_t)ch * 16 * HW + p;
        U16 a, b;
#pragma unroll
        for (int j = 0; j < 8; ++j) a.v[j] = (__bf16)src[(size_t)j * HW];
#pragma unroll
        for (int j = 0; j < 8; ++j) b.v[j] = (__bf16)src[(size_t)(8 + j) * HW];
        size_t o = loffE(lv) + (size_t)n * HW * 256 + (((size_t)ch * HW + p) << 4);
        *(uint4*)&x16[o] = a.q;
        *(uint4*)&x16[o + 8] = b.q;
    } else {
        int e16 = bid - 3008;
        for (int idx = tid; idx < 512; idx += 256) {
            int co = idx >> 4, j = idx & 15;
            float v = (co < 3) ? olw[co * 256 + e16 * 16 + j] : 0.f;
            olw32[e16 * 512 + co * 16 + j] = (__bf16)v;
        }
    }
}

// ---------------- conv 3x3 SAME v7: 512-px tiles, wave 64co x 128px ---------
// mode 0 (conv1, 448): 8 sharers (cg4 x br2) per T; mode 1 (conv2, 448):
// 4 sharers (cg) per T2=(T<<1|br); mode 2 (single branch, 224): 4 sharers.
// XCD-residue packed: id%8 == T%8 so all sharers of one input tile co-locate.
__global__ __launch_bounds__(256, 2) void conv3x3_v7(
    const __bf16* __restrict__ inA, const __bf16* __restrict__ inB,
    const __bf16* __restrict__ wtA, const __bf16* __restrict__ wtB,
    const float* __restrict__ bA, const float* __restrict__ bB,
    const __bf16* __restrict__ zrow,
    __bf16* __restrict__ outA, __bf16* __restrict__ outB, int mode)
{
    __shared__ __bf16 Asm[2][9216];   // 2 x 18 KB: [t][half][co64][8]

    const int id = blockIdx.x;
    const int r8 = id & 7, q = id >> 3;
    int cg, br, T;
    if (mode == 0) {
        int s = q & 7; cg = s & 3; br = s >> 2;
        T = ((q >> 3) << 3) + r8;                 // [0,56)
    } else if (mode == 1) {
        cg = q & 3;
        int T2 = ((q >> 2) << 3) + r8;            // [0,112)
        br = T2 & 1; T = T2 >> 1;
    } else {
        cg = q & 3; br = 0;
        T = ((q >> 2) << 3) + r8;                 // [0,56)
    }
    const int n = T & 1, tile = T >> 1;           // tile in [0,28)

    const int tid = threadIdx.x;
    const __bf16* in16 = br ? inB : inA;
    const __bf16* wt = br ? wtB : wtA;
    const float* bias = br ? bB : bA;
    __bf16* outp = br ? outB : outA;

    const int lv = (tile < 20) ? 0 : (tile < 25) ? 1 : (tile < 27) ? 2 : 3;
    const int tb = (lv == 0) ? 0 : (lv == 1) ? 20 : (lv == 2) ? 25 : 27;
    const int lg2W = 7 - lv;
    const int W = 1 << lg2W, H = 80 >> lv;
    const int HW = 10240 >> (2 * lv);
    const size_t ioff = loffE(lv) + (size_t)n * HW * 256;
    const __bf16* inb = in16 + ioff;

    const int p0 = (tile - tb) << 9;
    const int npix = min(512, HW - p0);

    const int w = tid >> 6, l64 = tid & 63;
    const int lane = l64 & 31, half = l64 >> 5;
    const int pxbase = p0 + (w << 7);
    const int cobase = cg << 6;

    // chunk-invariant per-tap byte offsets, 4 px slots (-1 = OOB)
    int bo[36];
#pragma unroll
    for (int s = 0; s < 4; ++s) {
        int pix = pxbase + (s << 5) + lane;
        int py = pix >> lg2W, px = pix & (W - 1);
#pragma unroll
        for (int dy = 0; dy < 3; ++dy)
#pragma unroll
            for (int dx = 0; dx < 3; ++dx) {
                int gy = py + dy - 1, gx = px + dx - 1;
                bo[(dy * 3 + dx) * 4 + s] =
                    ((unsigned)gy < (unsigned)H && (unsigned)gx < (unsigned)W)
                    ? (((gy << lg2W) + gx) * 32 + half * 16) : -1;
            }
    }
    const __bf16* zp = zrow + (half << 3);

    const char* wtb = (const char*)wt + (cg * 2048);
    auto stage = [&](int c16, int buf) {
        const char* base = wtb + (size_t)c16 * 8192;
        for (int u = w; u < 18; u += 4) {
            int t = u >> 1, hf = u & 1;
            async16(base + (size_t)t * 131072 + hf * 1024 + l64 * 16,
                    &Asm[buf][u * 512]);
        }
    };

    f32x16 acc[2][4] = {};

    stage(0, 0);
    int buf = 0;
    for (int c16 = 0; c16 < 16; ++c16) {
        __syncthreads();
        if (c16 < 15) stage(c16 + 1, buf ^ 1);
        const char* curB = (const char*)inb + (size_t)c16 * HW * 32;
        const __bf16* Ab = &Asm[buf][0];
#pragma unroll
        for (int t = 0; t < 9; ++t) {
            bf16x8 a0 = *(const bf16x8*)&Ab[t * 1024 + half * 512 + lane * 8];
            bf16x8 a1 = *(const bf16x8*)&Ab[t * 1024 + half * 512 + 256 + lane * 8];
            bf16x8 b[4];
#pragma unroll
            for (int s = 0; s < 4; ++s) {
                int o = bo[t * 4 + s];
                const __bf16* qp = (o >= 0) ? (const __bf16*)(curB + o) : zp;
                b[s] = *(const bf16x8*)qp;
            }
#pragma unroll
            for (int s = 0; s < 4; ++s) {
                acc[0][s] = __builtin_amdgcn_mfma_f32_32x32x16_bf16(a0, b[s], acc[0][s], 0, 0, 0);
                acc[1][s] = __builtin_amdgcn_mfma_f32_32x32x16_bf16(a1, b[s], acc[1][s], 0, 0, 0);
            }
        }
        buf ^= 1;
    }
    // epilogue: per frag col=lane (pixel), row=(reg&3)+8*(reg>>2)+4*half (co)
#pragma unroll
    for (int s = 0; s < 4; ++s) {
        const bool ok = ((w << 7) + (s << 5)) < npix;
        if (!ok) continue;
        const int pixg = pxbase + (s << 5) + lane;
#pragma unroll
        for (int f = 0; f < 2; ++f) {
            const f32x16& A = acc[f][s];
#pragma unroll
            for (int qq = 0; qq < 4; ++qq) {
                int co0 = cobase + f * 32 + qq * 8 + half * 4;
                float4 bq = *(const float4*)&bias[co0];
                U8 v;
                v.h[0] = (__bf16)fmaxf(A[qq * 4 + 0] + bq.x, 0.f);
                v.h[1] = (__bf16)fmaxf(A[qq * 4 + 1] + bq.y, 0.f);
                v.h[2] = (__bf16)fmaxf(A[qq * 4 + 2] + bq.z, 0.f);
                v.h[3] = (__bf16)fmaxf(A[qq * 4 + 3] + bq.w, 0.f);
                size_t base = ioff + (((size_t)(co0 >> 4) * HW) << 4) + (co0 & 15);
                *(unsigned long long*)&outp[base + ((size_t)pixg << 4)] = v.u;
            }
        }
    }
}

// ---------------- merged 1x1 heads ------------------------------------------
__global__ __launch_bounds__(256) void heads_k(
    const __bf16* __restrict__ h16p, const __bf16* __restrict__ h16o,
    const float* __restrict__ plw, const float* __restrict__ plb,
    const float* __restrict__ pdw, const float* __restrict__ pdb,
    const float* __restrict__ odw, const float* __restrict__ odb,
    float* __restrict__ out, float* __restrict__ scores)
{
    int bx = blockIdx.x, n = blockIdx.y, br = blockIdx.z;
    int lv = lvl256(bx);
    int HW = 10240 >> (2 * lv);
    int p = (bx - tbase256(lv)) * 256 + threadIdx.x;
    if (p >= HW) return;
    size_t ioff = loffE(lv) + (size_t)n * HW * 256;
    if (br == 0) {
        float acc[15];
#pragma unroll
        for (int a = 0; a < 15; ++a) acc[a] = 0.f;
        for (int ch = 0; ch < 16; ++ch) {
            size_t base = ioff + (((size_t)ch * HW + p) << 4);
            bf16x8 v0 = *(const bf16x8*)&h16p[base];
            bf16x8 v1 = *(const bf16x8*)&h16p[base + 8];
#pragma unroll
            for (int j = 0; j < 16; ++j) {
                float vv = (j < 8) ? (float)v0[j] : (float)v1[j - 8];
                int c = ch * 16 + j;
#pragma unroll
                for (int a = 0; a < 3; ++a)  acc[a]     = fmaf(plw[a * 256 + c], vv, acc[a]);
#pragma unroll
                for (int a = 0; a < 12; ++a) acc[3 + a] = fmaf(pdw[a * 256 + c], vv, acc[3 + a]);
            }
        }
        float sc = -INFINITY;
#pragma unroll
        for (int a = 0; a < 3; ++a) {
            float lg = acc[a] + plb[a];
            out[plog_off(lv) + ((size_t)n * 3 + a) * HW + p] = lg;
            sc = fmaxf(sc, lg);
        }
        scores[soff_l(lv) + (size_t)n * HW + p] = sc;
#pragma unroll
        for (int a = 0; a < 12; ++a)
            out[pdel_off(lv) + ((size_t)n * 12 + a) * HW + p] = acc[3 + a] + pdb[a];
    } else {
        float acc[12];
#pragma unroll
        for (int a = 0; a < 12; ++a) acc[a] = 0.f;
        for (int ch = 0; ch < 16; ++ch) {
            size_t base = ioff + (((size_t)ch * HW + p) << 4);
            bf16x8 v0 = *(const bf16x8*)&h16o[base];
            bf16x8 v1 = *(const bf16x8*)&h16o[base + 8];
#pragma unroll
            for (int j = 0; j < 16; ++j) {
                float vv = (j < 8) ? (float)v0[j] : (float)v1[j - 8];
                int c = ch * 16 + j;
#pragma unroll
                for (int a = 0; a < 12; ++a) acc[a] = fmaf(odw[a * 256 + c], vv, acc[a]);
            }
        }
#pragma unroll
        for (int a = 0; a < 12; ++a)
            out[odel_off(lv) + ((size_t)n * 12 + a) * HW + p] = acc[a] + odb[a];
    }
}

// ---------------- per-level top-20 ------------------------------------------
__global__ __launch_bounds__(256) void topk_lvl_k(
    const float* __restrict__ scores, float* __restrict__ lv_sc,
    int* __restrict__ lv_ix)
{
    int l = blockIdx.x, n = blockIdx.y;
    int HW = 10240 >> (2 * l);
    const float* sp = scores + soff_l(l) + (size_t)n * HW;
    int tid = threadIdx.x;
    __shared__ float sc[10240];
    __shared__ float wv4[4];
    __shared__ int wi4[4];
    __shared__ int bcast;
    for (int i = tid; i < HW; i += 256) sc[i] = sp[i];
    __syncthreads();
    float bv = -INFINITY; int bi = 0x7fffffff;
    for (int i = tid; i < HW; i += 256)
        if (sc[i] > bv) { bv = sc[i]; bi = i; }
    const int w = tid >> 6, lane = tid & 63;
    for (int r = 0; r < 20; ++r) {
        float cv = bv; int ci = bi;
#pragma unroll
        for (int off = 32; off > 0; off >>= 1) {
            float ov = __shfl_xor(cv, off);
            int oi = __shfl_xor(ci, off);
            if (ov > cv || (ov == cv && oi < ci)) { cv = ov; ci = oi; }
        }
        if (lane == 0) { wv4[w] = cv; wi4[w] = ci; }
        __syncthreads();
        if (tid == 0) {
            float mv = wv4[0]; int mi = wi4[0];
#pragma unroll
            for (int j = 1; j < 4; ++j)
                if (wv4[j] > mv || (wv4[j] == mv && wi4[j] < mi)) { mv = wv4[j]; mi = wi4[j]; }
            bcast = mi;
            int idx = (n * 4 + l) * 20 + r;
            lv_sc[idx] = mv;
            lv_ix[idx] = mi;
        }
        __syncthreads();
        int mi = bcast;
        if ((mi & 255) == tid) {
            sc[mi] = -INFINITY;
            bv = -INFINITY; bi = 0x7fffffff;
            for (int i = tid; i < HW; i += 256)
                if (sc[i] > bv) { bv = sc[i]; bi = i; }
        }
    }
}

// ---------------- global select 20-of-80 + gather pf + pproj ----------------
__global__ __launch_bounds__(256) void sel_pproj_k(
    const float* __restrict__ lv_sc, const int* __restrict__ lv_ix,
    const __bf16* __restrict__ h16p, const float* __restrict__ WpT,
    const float* __restrict__ rn1b, float* __restrict__ pp)
{
    int n = blockIdx.x, tid = threadIdx.x;
    __shared__ int selL[20], selC[20];
    __shared__ float pfL[5120];
    __shared__ float wv2[2];
    __shared__ int wi2[2];
    __shared__ int bcast;
    float bv = -INFINITY; int bi = 0x7fffffff;
    if (tid < 80) { bv = lv_sc[n * 80 + tid]; bi = tid; }
    const int w = tid >> 6, lane = tid & 63;
    for (int r = 0; r < 20; ++r) {
        float cv = bv; int ci = bi;
#pragma unroll
        for (int off = 32; off > 0; off >>= 1) {
            float ov = __shfl_xor(cv, off);
            int oi = __shfl_xor(ci, off);
            if (ov > cv || (ov == cv && oi < ci)) { cv = ov; ci = oi; }
        }
        if (lane == 0 && w < 2) { wv2[w] = cv; wi2[w] = ci; }
        __syncthreads();
        if (tid == 0) {
            float mv = wv2[0]; int mi = wi2[0];
            if (wv2[1] > mv || (wv2[1] == mv && wi2[1] < mi)) { mv = wv2[1]; mi = wi2[1]; }
            bcast = mi;
            selL[r] = mi / 20;
            selC[r] = lv_ix[n * 80 + mi];
        }
        __syncthreads();
        if (bcast == bi) bv = -INFINITY;
    }
    for (int t = tid; t < 5120; t += 256) {
        int k = t >> 8, c = t & 255;
        int l = selL[k], cell = selC[k];
        int HW = 10240 >> (2 * l);
        pfL[k * 256 + c] =
            (float)h16p[loffE(l) + (size_t)n * HW * 256 +
                        (((size_t)(c >> 4) * HW + cell) << 4) + (c & 15)];
    }
    __syncthreads();
    float acc[20];
    float bb = rn1b[tid];
#pragma unroll
    for (int k = 0; k < 20; ++k) acc[k] = bb;
    for (int c = 0; c < 256; ++c) {
        float wv = WpT[c * 256 + tid];
#pragma unroll
        for (int k = 0; k < 20; ++k) acc[k] = fmaf(pfL[k * 256 + c], wv, acc[k]);
    }
#pragma unroll
    for (int k = 0; k < 20; ++k)
        pp[(size_t)n * 5120 + k * 256 + tid] = acc[k];
}

// ---------------- fused o_proj + hsum + rn2 + MFMA-ol -----------------------
__global__ __launch_bounds__(256) void orel_k(
    const __bf16* __restrict__ H16o, const __bf16* __restrict__ Wo16,
    const __bf16* __restrict__ rn216, const __bf16* __restrict__ olw32,
    const float* __restrict__ pp, const float* __restrict__ rn2b,
    const float* __restrict__ olb, float* __restrict__ out)
{
    __shared__ __bf16 hb[16 * 64 * 24];
    __shared__ __bf16 pp16[5120];
    __shared__ float red[768];
    const int tid = threadIdx.x;
    const int n = blockIdx.y;
    int bx = blockIdx.x;
    int lv = (bx < 160) ? 0 : (bx < 200) ? 1 : (bx < 210) ? 2 : 3;
    int tb = (lv == 0) ? 0 : (lv == 1) ? 160 : (lv == 2) ? 200 : 210;
    int HW = 10240 >> (2 * lv);
    size_t yoff = loffE(lv) + (size_t)n * HW * 256;
    int p0 = (bx - tb) << 6;
    int npix = min(64, HW - p0);

    {
        const float* ps = pp + (size_t)n * 5120;
        for (int i = tid; i < 1280; i += 256) {
            float4 f = *(const float4*)&ps[i * 4];
            U8 v;
            v.h[0] = (__bf16)f.x; v.h[1] = (__bf16)f.y;
            v.h[2] = (__bf16)f.z; v.h[3] = (__bf16)f.w;
            *(unsigned long long*)&pp16[i * 4] = v.u;
        }
    }
    __syncthreads();

    const int w = tid >> 6, l64 = tid & 63;
    const int lane = l64 & 31, half = l64 >> 5;
    const int dbase = w << 6;

    f32x16 acc00 = {}, acc01 = {}, acc10 = {}, acc11 = {};
    for (int c16 = 0; c16 < 16; ++c16) {
        bf16x8 a0 = *(const bf16x8*)&Wo16[(((c16 << 8) + dbase + lane) << 4) + (half << 3)];
        bf16x8 a1 = *(const bf16x8*)&Wo16[(((c16 << 8) + dbase + 32 + lane) << 4) + (half << 3)];
        bf16x8 b0 = *(const bf16x8*)&H16o[yoff + (((size_t)c16 * HW + p0 + lane) << 4) + (half << 3)];
        bf16x8 b1 = *(const bf16x8*)&H16o[yoff + (((size_t)c16 * HW + p0 + 32 + lane) << 4) + (half << 3)];
        acc00 = __builtin_amdgcn_mfma_f32_32x32x16_bf16(a0, b0, acc00, 0, 0, 0);
        acc01 = __builtin_amdgcn_mfma_f32_32x32x16_bf16(a0, b1, acc01, 0, 0, 0);
        acc10 = __builtin_amdgcn_mfma_f32_32x32x16_bf16(a1, b0, acc10, 0, 0, 0);
        acc11 = __builtin_amdgcn_mfma_f32_32x32x16_bf16(a1, b1, acc11, 0, 0, 0);
    }
#pragma unroll
    for (int b = 0; b < 2; ++b) {
        const f32x16& A0 = b ? acc10 : acc00;
        const f32x16& A1 = b ? acc11 : acc01;
#pragma unroll
        for (int q = 0; q < 4; ++q) {
            int d0 = dbase + b * 32 + q * 8 + half * 4;
            float h0[4] = {0.f, 0.f, 0.f, 0.f}, h1[4] = {0.f, 0.f, 0.f, 0.f};
            for (int k = 0; k < 20; ++k) {
                U8 pk;
                pk.u = *(const unsigned long long*)&pp16[k * 256 + d0];
#pragma unroll
                for (int j = 0; j < 4; ++j) {
                    float pkv = (float)pk.h[j];
                    h0[j] += fmaxf(A0[q * 4 + j] + pkv, 0.f);
                    h1[j] += fmaxf(A1[q * 4 + j] + pkv, 0.f);
                }
            }
            U8 v0, v1;
#pragma unroll
            for (int j = 0; j < 4; ++j) { v0.h[j] = (__bf16)h0[j]; v1.h[j] = (__bf16)h1[j]; }
            *(unsigned long long*)&hb[((d0 >> 4) * 64 + lane) * 24 + (d0 & 15)] = v0.u;
            *(unsigned long long*)&hb[((d0 >> 4) * 64 + 32 + lane) * 24 + (d0 & 15)] = v1.u;
        }
    }
    __syncthreads();
    f32x16 e00 = {}, e01 = {}, e10 = {}, e11 = {};
    for (int d16 = 0; d16 < 16; ++d16) {
        bf16x8 a0 = *(const bf16x8*)&rn216[(((d16 << 8) + dbase + lane) << 4) + (half << 3)];
        bf16x8 a1 = *(const bf16x8*)&rn216[(((d16 << 8) + dbase + 32 + lane) << 4) + (half << 3)];
        bf16x8 b0 = *(const bf16x8*)&hb[(d16 * 64 + lane) * 24 + (half << 3)];
        bf16x8 b1 = *(const bf16x8*)&hb[(d16 * 64 + 32 + lane) * 24 + (half << 3)];
        e00 = __builtin_amdgcn_mfma_f32_32x32x16_bf16(a0, b0, e00, 0, 0, 0);
        e01 = __builtin_amdgcn_mfma_f32_32x32x16_bf16(a0, b1, e01, 0, 0, 0);
        e10 = __builtin_amdgcn_mfma_f32_32x32x16_bf16(a1, b0, e10, 0, 0, 0);
        e11 = __builtin_amdgcn_mfma_f32_32x32x16_bf16(a1, b1, e11, 0, 0, 0);
    }
    __syncthreads();
#pragma unroll
    for (int b = 0; b < 2; ++b) {
        const f32x16& A0 = b ? e10 : e00;
        const f32x16& A1 = b ? e11 : e01;
#pragma unroll
        for (int q = 0; q < 4; ++q) {
            int e0 = dbase + b * 32 + q * 8 + half * 4;
            float4 bb = *(const float4*)&rn2b[e0];
            U8 v0, v1;
            v0.h[0] = (__bf16)fmaxf(A0[q * 4 + 0] + bb.x, 0.f);
            v0.h[1] = (__bf16)fmaxf(A0[q * 4 + 1] + bb.y, 0.f);
            v0.h[2] = (__bf16)fmaxf(A0[q * 4 + 2] + bb.z, 0.f);
            v0.h[3] = (__bf16)fmaxf(A0[q * 4 + 3] + bb.w, 0.f);
            v1.h[0] = (__bf16)fmaxf(A1[q * 4 + 0] + bb.x, 0.f);
            v1.h[1] = (__bf16)fmaxf(A1[q * 4 + 1] + bb.y, 0.f);
            v1.h[2] = (__bf16)fmaxf(A1[q * 4 + 2] + bb.z, 0.f);
            v1.h[3] = (__bf16)fmaxf(A1[q * 4 + 3] + bb.w, 0.f);
            *(unsigned long long*)&hb[((e0 >> 4) * 64 + lane) * 24 + (e0 & 15)] = v0.u;
            *(unsigned long long*)&hb[((e0 >> 4) * 64 + 32 + lane) * 24 + (e0 & 15)] = v1.u;
        }
    }
    __syncthreads();
    f32x16 ol0 = {}, ol1 = {};
#pragma unroll
    for (int j = 0; j < 4; ++j) {
        int e16 = w * 4 + j;
        bf16x8 a = *(const bf16x8*)&olw32[e16 * 512 + lane * 16 + (half << 3)];
        bf16x8 b0 = *(const bf16x8*)&hb[(e16 * 64 + lane) * 24 + (half << 3)];
        bf16x8 b1 = *(const bf16x8*)&hb[(e16 * 64 + 32 + lane) * 24 + (half << 3)];
        ol0 = __builtin_amdgcn_mfma_f32_32x32x16_bf16(a, b0, ol0, 0, 0, 0);
        ol1 = __builtin_amdgcn_mfma_f32_32x32x16_bf16(a, b1, ol1, 0, 0, 0);
    }
    if (half == 0) {
#pragma unroll
        for (int r = 0; r < 3; ++r) {
            red[(r * 64 + lane) * 4 + w] = ol0[r];
            red[(r * 64 + lane + 32) * 4 + w] = ol1[r];
        }
    }
    __syncthreads();
    if (tid < 192) {
        int a = tid >> 6, px = tid & 63;
        if (px < npix) {
            float4 p4 = *(const float4*)&red[(a * 64 + px) * 4];
            out[olog_off(lv) + ((size_t)n * 3 + a) * HW + p0 + px] =
                olb[a] + p4.x + p4.y + p4.z + p4.w;
        }
    }
}

extern "C" void kernel_launch(void* const* d_in, const int* in_sizes, int n_in,
                              void* d_out, int out_size, void* d_ws, size_t ws_size,
                              hipStream_t stream)
{
    const float* feat[4] = {(const float*)d_in[0], (const float*)d_in[1],
                            (const float*)d_in[2], (const float*)d_in[3]};
    const float* pc1w = (const float*)d_in[4];  const float* pc1b = (const float*)d_in[5];
    const float* pc2w = (const float*)d_in[6];  const float* pc2b = (const float*)d_in[7];
    const float* oc1w = (const float*)d_in[8];  const float* oc1b = (const float*)d_in[9];
    const float* oc2w = (const float*)d_in[10]; const float* oc2b = (const float*)d_in[11];
    const float* rn1w = (const float*)d_in[12]; const float* rn1b = (const float*)d_in[13];
    const float* rn2w = (const float*)d_in[14]; const float* rn2b = (const float*)d_in[15];
    const float* plw  = (const float*)d_in[16]; const float* plb  = (const float*)d_in[17];
    const float* pdw  = (const float*)d_in[18]; const float* pdb  = (const float*)d_in[19];
    const float* olw  = (const float*)d_in[20]; const float* olb  = (const float*)d_in[21];
    const float* odw  = (const float*)d_in[22]; const float* odb  = (const float*)d_in[23];

    float* ws = (float*)d_ws;
    __bf16* bufA = (__bf16*)(ws);             // X16 -> H16p
    __bf16* bufB = (__bf16*)(ws + 3481600);   // Y16p -> (fallback) H16o
    __bf16* bufC = (__bf16*)(ws + 6963200);   // Y16o
    __bf16* wtap = (__bf16*)(ws + 10444800);  // 4 x 589824 bf16
    __bf16* wt_pc1 = wtap;
    __bf16* wt_pc2 = wtap + 589824;
    __bf16* wt_oc1 = wtap + 2 * 589824;
    __bf16* wt_oc2 = wtap + 3 * 589824;
    __bf16* Wo16  = (__bf16*)(ws + 11624448);
    __bf16* rn216 = (__bf16*)(ws + 11657216);
    float* WpT    = ws + 11689984;
    float* scores = ws + 11755520;
    float* lv_sc  = ws + 11783040;
    int*   lv_ix  = (int*)(ws + 11783200);
    __bf16* olw32 = (__bf16*)(ws + 11783360);   // 8192 bf16
    float* pp     = ws + 11793280;
    __bf16* zrow  = (__bf16*)(ws + 11803520);
    __bf16* bufD  = (__bf16*)(ws + 11803904);   // optional H16o (merged path)
    float* out    = (float*)d_out;

    const bool merged = ws_size >= (size_t)(11803904 + 3481600) * 4;

    hipLaunchKernelGGL(prep_all_k, dim3(3024), dim3(256), 0, stream,
                       feat[0], feat[1], feat[2], feat[3],
                       pc1w, pc2w, oc1w, oc2w, rn1w, rn2w, olw,
                       wtap, WpT, Wo16, rn216, olw32, (unsigned*)zrow, bufA);

    // conv1 (mode 0): p -> bufB, o -> bufC
    hipLaunchKernelGGL(conv3x3_v7, dim3(448), dim3(256), 0, stream,
                       bufA, bufA, wt_pc1, wt_oc1, pc1b, oc1b, zrow,
                       bufB, bufC, 0);

    __bf16* h16o;
    if (merged) {
        hipLaunchKernelGGL(conv3x3_v7, dim3(448), dim3(256), 0, stream,
                           bufB, bufC, wt_pc2, wt_oc2, pc2b, oc2b, zrow,
                           bufA, bufD, 1);
        h16o = bufD;
    } else {
        hipLaunchKernelGGL(conv3x3_v7, dim3(224), dim3(256), 0, stream,
                           bufB, bufB, wt_pc2, wt_pc2, pc2b, pc2b, zrow,
                           bufA, bufA, 2);
        hipLaunchKernelGGL(conv3x3_v7, dim3(224), dim3(256), 0, stream,
                           bufC, bufC, wt_oc2, wt_oc2, oc2b, oc2b, zrow,
                           bufB, bufB, 2);
        h16o = bufB;
    }

    hipLaunchKernelGGL(heads_k, dim3(54, 2, 2), dim3(256), 0, stream,
                       bufA, h16o, plw, plb, pdw, pdb, odw, odb, out, scores);

    hipLaunchKernelGGL(topk_lvl_k, dim3(4, 2), dim3(256), 0, stream,
                       scores, lv_sc, lv_ix);
    hipLaunchKernelGGL(sel_pproj_k, dim3(2), dim3(256), 0, stream,
                       lv_sc, lv_ix, bufA, WpT, rn1b, pp);

    hipLaunchKernelGGL(orel_k, dim3(213, 2), dim3(256), 0, stream,
                       h16o, Wo16, rn216, olw32, pp, rn2b, olb, out);
}

// Round 10
// 497.212 us; speedup vs baseline: 1.1685x; 1.1685x over previous
//
#include <hip/hip_runtime.h>
#include <cstdint>
#include <cstddef>

typedef __bf16 bf16x8 __attribute__((ext_vector_type(8)));
typedef float  f32x16 __attribute__((ext_vector_type(16)));

union U16 { bf16x8 v; uint4 q; };
union U8  { __bf16 h[4]; unsigned long long u; };

typedef __attribute__((address_space(1))) const unsigned char gas_t;
typedef __attribute__((address_space(3))) unsigned char las_t;
__device__ __forceinline__ void async16(const void* g, void* l) {
    __builtin_amdgcn_global_load_lds((gas_t*)g, (las_t*)l, 16, 0, 0);
}

// level helpers (256-pixel tiles): tile counts 40,10,3,1 -> bounds 40,50,53,54
__device__ __forceinline__ int lvl256(int bx) {
    return (bx < 40) ? 0 : (bx < 50) ? 1 : (bx < 53) ? 2 : 3;
}
__device__ __forceinline__ int tbase256(int lv) {
    return (lv == 0) ? 0 : (lv == 1) ? 40 : (lv == 2) ? 50 : 53;
}
__device__ __forceinline__ size_t loffE(int lv) {
    return (lv == 0) ? 0 : (lv == 1) ? 5242880 : (lv == 2) ? 6553600 : 6881280;
}
__device__ __forceinline__ size_t plog_off(int lv) {
    return (lv == 0) ? 0 : (lv == 1) ? 61440 : (lv == 2) ? 76800 : 80640;
}
__device__ __forceinline__ size_t pdel_off(int lv) {
    return (lv == 0) ? 81600 : (lv == 1) ? 327360 : (lv == 2) ? 388800 : 404160;
}
__device__ __forceinline__ size_t olog_off(int lv) {
    return (lv == 0) ? 408000 : (lv == 1) ? 469440 : (lv == 2) ? 484800 : 488640;
}
__device__ __forceinline__ size_t odel_off(int lv) {
    return (lv == 0) ? 489600 : (lv == 1) ? 735360 : (lv == 2) ? 796800 : 812160;
}
__device__ __forceinline__ int soff_l(int lv) {
    return (lv == 0) ? 0 : (lv == 1) ? 20480 : (lv == 2) ? 25600 : 26880;
}

// ---------------- fused prep, grid 3024 --------------------------------------
__global__ __launch_bounds__(256) void prep_all_k(
    const float* f0, const float* f1, const float* f2, const float* f3,
    const float* pc1w, const float* pc2w, const float* oc1w, const float* oc2w,
    const float* __restrict__ rn1w, const float* __restrict__ rn2w,
    const float* __restrict__ olw,
    __bf16* __restrict__ wtap, float* __restrict__ WpT,
    __bf16* __restrict__ Wo16, __bf16* __restrict__ rn216,
    __bf16* __restrict__ olw32,
    unsigned* __restrict__ zrow32, __bf16* __restrict__ x16)
{
    __shared__ float f[2304];
    int bid = blockIdx.x, tid = threadIdx.x;
    if (bid < 1024) {
        int which = bid >> 8, co = bid & 255;
        const float* srcw = (which == 0) ? pc1w : (which == 1) ? pc2w
                          : (which == 2) ? oc1w : oc2w;
        const float* src = srcw + (size_t)co * 2304;
        for (int i = tid; i < 2304; i += 256) f[i] = src[i];
        __syncthreads();
        __bf16* dst = wtap + (size_t)which * 589824;
        int cg = co >> 6, co64 = co & 63;
        for (int u = tid; u < 288; u += 256) {
            int t = u >> 5, rest = u & 31, c16 = rest >> 1, hf = rest & 1;
            int ci0 = c16 * 16 + hf * 8;
            U16 v;
#pragma unroll
            for (int j = 0; j < 8; ++j) v.v[j] = (__bf16)f[(ci0 + j) * 9 + t];
            *(uint4*)&dst[(size_t)t * 65536 + c16 * 4096 + cg * 1024 + hf * 512 + co64 * 8] = v.q;
        }
    } else if (bid < 1280) {
        int d = bid - 1024, c = tid;
        WpT[c * 256 + d] = rn1w[(size_t)d * 512 + 256 + c];
        Wo16[((c >> 4) * 256 + d) * 16 + (c & 15)] = (__bf16)rn1w[(size_t)d * 512 + c];
        rn216[((c >> 4) * 256 + d) * 16 + (c & 15)] = (__bf16)rn2w[(size_t)d * 256 + c];
        if (d == 0) zrow32[c] = 0u;
    } else if (bid < 3008) {
        int u = bid - 1280;
        int bx = u >> 5, rr = u & 31, n = rr >> 4, ch = rr & 15;
        int lv = lvl256(bx);
        int HW = 10240 >> (2 * lv);
        int p = (bx - tbase256(lv)) * 256 + tid;
        if (p >= HW) return;
        const float* fp = (lv == 0) ? f0 : (lv == 1) ? f1 : (lv == 2) ? f2 : f3;
        const float* src = fp + (size_t)n * 256 * HW + (size_t)ch * 16 * HW + p;
        U16 a, b;
#pragma unroll
        for (int j = 0; j < 8; ++j) a.v[j] = (__bf16)src[(size_t)j * HW];
#pragma unroll
        for (int j = 0; j < 8; ++j) b.v[j] = (__bf16)src[(size_t)(8 + j) * HW];
        size_t o = loffE(lv) + (size_t)n * HW * 256 + (((size_t)ch * HW + p) << 4);
        *(uint4*)&x16[o] = a.q;
        *(uint4*)&x16[o + 8] = b.q;
    } else {
        int e16 = bid - 3008;
        for (int idx = tid; idx < 512; idx += 256) {
            int co = idx >> 4, j = idx & 15;
            float v = (co < 3) ? olw[co * 256 + e16 * 16 + j] : 0.f;
            olw32[e16 * 512 + co * 16 + j] = (__bf16)v;
        }
    }
}

// ---------------- conv 3x3 SAME: XCD-swizzled 1-D grid, LDS-A + global-B ----
// mode 0 (conv1, 896 blk): c8 = by+4br share one input (T = tile*2+n)
// mode 1 (conv2 merged, 864): c4 = by; T2 = (tile*2+n)*2+br
// mode 2 (single branch, 448): c4 = by; T = tile*2+n
__global__ __launch_bounds__(256, 3) void conv3x3_v6(
    const __bf16* __restrict__ inA, const __bf16* __restrict__ inB,
    const __bf16* __restrict__ wtA, const __bf16* __restrict__ wtB,
    const float* __restrict__ bA, const float* __restrict__ bB,
    const __bf16* __restrict__ zrow,
    __bf16* __restrict__ outA, __bf16* __restrict__ outB, int mode)
{
    __shared__ __bf16 Asm[2][9216];   // 2 x 18 KB: [t][half][co64][8]

    const int id = blockIdx.x;
    const int r8 = id & 7, q = id >> 3;
    int by, br, n, tile;
    if (mode == 0) {
        by = q & 3; br = (q >> 2) & 1;
        int T = ((q >> 3) << 3) + r8; if (T >= 108) return;
        n = T & 1; tile = T >> 1;
    } else if (mode == 1) {
        by = q & 3;
        int T2 = ((q >> 2) << 3) + r8; if (T2 >= 216) return;
        br = T2 & 1; n = (T2 >> 1) & 1; tile = T2 >> 2;
    } else {
        by = q & 3; br = 0;
        int T = ((q >> 2) << 3) + r8; if (T >= 108) return;
        n = T & 1; tile = T >> 1;
    }

    const int tid = threadIdx.x;
    const __bf16* in16 = br ? inB : inA;
    const __bf16* wt = br ? wtB : wtA;
    const float* bias = br ? bB : bA;
    __bf16* outp = br ? outB : outA;

    const int lv = lvl256(tile);
    const int lg2W = 7 - lv;
    const int W = 1 << lg2W, H = 80 >> lv;
    const int HW = 10240 >> (2 * lv);
    const size_t ioff = loffE(lv) + (size_t)n * HW * 256;
    const __bf16* inb = in16 + ioff;

    const int sp0 = (tile - tbase256(lv)) << 8;
    const int npix = min(256, HW - sp0);

    const int w = tid >> 6, l64 = tid & 63;
    const int lane = l64 & 31, half = l64 >> 5;
    const int pix0 = (w << 6) + lane, pix1 = pix0 + 32;
    const int cobase = by << 6;

    int boff0[9], boff1[9];
    {
        const int y0 = sp0 >> lg2W;
        const int py0 = pix0 >> lg2W, px0 = pix0 & (W - 1);
        const int py1 = pix1 >> lg2W, px1 = pix1 & (W - 1);
#pragma unroll
        for (int dy = 0; dy < 3; ++dy)
#pragma unroll
            for (int dx = 0; dx < 3; ++dx) {
                int t = dy * 3 + dx;
                int gy0 = y0 + py0 + dy - 1, gx0 = px0 + dx - 1;
                boff0[t] = ((unsigned)gy0 < (unsigned)H && (unsigned)gx0 < (unsigned)W)
                           ? (((gy0 << lg2W) + gx0) * 32 + half * 16) : -1;
                int gy1 = y0 + py1 + dy - 1, gx1 = px1 + dx - 1;
                boff1[t] = ((unsigned)gy1 < (unsigned)H && (unsigned)gx1 < (unsigned)W)
                           ? (((gy1 << lg2W) + gx1) * 32 + half * 16) : -1;
            }
    }
    const __bf16* zp = zrow + (half << 3);

    const char* wtb = (const char*)wt + (by * 2048);
    auto stage = [&](int c16, int buf) {
        const char* base = wtb + (size_t)c16 * 8192;
        for (int u = w; u < 18; u += 4) {
            int t = u >> 1, hf = u & 1;
            async16(base + (size_t)t * 131072 + hf * 1024 + l64 * 16,
                    &Asm[buf][u * 512]);
        }
    };

    f32x16 acc00 = {}, acc01 = {}, acc10 = {}, acc11 = {};

    stage(0, 0);
    int buf = 0;
    for (int c16 = 0; c16 < 16; ++c16) {
        __syncthreads();
        if (c16 < 15) stage(c16 + 1, buf ^ 1);
        const char* curB = (const char*)inb + (size_t)c16 * HW * 32;
        const __bf16* Ab = &Asm[buf][0];
#pragma unroll
        for (int t = 0; t < 9; ++t) {
            bf16x8 a0 = *(const bf16x8*)&Ab[t * 1024 + half * 512 + lane * 8];
            bf16x8 a1 = *(const bf16x8*)&Ab[t * 1024 + half * 512 + 256 + lane * 8];
            const __bf16* q0 = (boff0[t] >= 0) ? (const __bf16*)(curB + boff0[t]) : zp;
            const __bf16* q1 = (boff1[t] >= 0) ? (const __bf16*)(curB + boff1[t]) : zp;
            bf16x8 b0 = *(const bf16x8*)q0;
            bf16x8 b1 = *(const bf16x8*)q1;
            acc00 = __builtin_amdgcn_mfma_f32_32x32x16_bf16(a0, b0, acc00, 0, 0, 0);
            acc01 = __builtin_amdgcn_mfma_f32_32x32x16_bf16(a0, b1, acc01, 0, 0, 0);
            acc10 = __builtin_amdgcn_mfma_f32_32x32x16_bf16(a1, b0, acc10, 0, 0, 0);
            acc11 = __builtin_amdgcn_mfma_f32_32x32x16_bf16(a1, b1, acc11, 0, 0, 0);
        }
        buf ^= 1;
    }
    const int pixg0 = sp0 + pix0, pixg1 = sp0 + pix1;
    const bool ok0 = (pix0 < npix), ok1 = (pix1 < npix);
#pragma unroll
    for (int b = 0; b < 2; ++b) {
        const f32x16& A0 = b ? acc10 : acc00;
        const f32x16& A1 = b ? acc11 : acc01;
#pragma unroll
        for (int qq = 0; qq < 4; ++qq) {
            int co0 = cobase + b * 32 + qq * 8 + half * 4;
            float4 bq = *(const float4*)&bias[co0];
            U8 v0, v1;
            v0.h[0] = (__bf16)fmaxf(A0[qq * 4 + 0] + bq.x, 0.f);
            v0.h[1] = (__bf16)fmaxf(A0[qq * 4 + 1] + bq.y, 0.f);
            v0.h[2] = (__bf16)fmaxf(A0[qq * 4 + 2] + bq.z, 0.f);
            v0.h[3] = (__bf16)fmaxf(A0[qq * 4 + 3] + bq.w, 0.f);
            v1.h[0] = (__bf16)fmaxf(A1[qq * 4 + 0] + bq.x, 0.f);
            v1.h[1] = (__bf16)fmaxf(A1[qq * 4 + 1] + bq.y, 0.f);
            v1.h[2] = (__bf16)fmaxf(A1[qq * 4 + 2] + bq.z, 0.f);
            v1.h[3] = (__bf16)fmaxf(A1[qq * 4 + 3] + bq.w, 0.f);
            size_t base = ioff + (((size_t)(co0 >> 4) * HW) << 4) + (co0 & 15);
            if (ok0) *(unsigned long long*)&outp[base + ((size_t)pixg0 << 4)] = v0.u;
            if (ok1) *(unsigned long long*)&outp[base + ((size_t)pixg1 << 4)] = v1.u;
        }
    }
}

// ---------------- merged 1x1 heads ------------------------------------------
__global__ __launch_bounds__(256) void heads_k(
    const __bf16* __restrict__ h16p, const __bf16* __restrict__ h16o,
    const float* __restrict__ plw, const float* __restrict__ plb,
    const float* __restrict__ pdw, const float* __restrict__ pdb,
    const float* __restrict__ odw, const float* __restrict__ odb,
    float* __restrict__ out, float* __restrict__ scores)
{
    int bx = blockIdx.x, n = blockIdx.y, br = blockIdx.z;
    int lv = lvl256(bx);
    int HW = 10240 >> (2 * lv);
    int p = (bx - tbase256(lv)) * 256 + threadIdx.x;
    if (p >= HW) return;
    size_t ioff = loffE(lv) + (size_t)n * HW * 256;
    if (br == 0) {
        float acc[15];
#pragma unroll
        for (int a = 0; a < 15; ++a) acc[a] = 0.f;
        for (int ch = 0; ch < 16; ++ch) {
            size_t base = ioff + (((size_t)ch * HW + p) << 4);
            bf16x8 v0 = *(const bf16x8*)&h16p[base];
            bf16x8 v1 = *(const bf16x8*)&h16p[base + 8];
#pragma unroll
            for (int j = 0; j < 16; ++j) {
                float vv = (j < 8) ? (float)v0[j] : (float)v1[j - 8];
                int c = ch * 16 + j;
#pragma unroll
                for (int a = 0; a < 3; ++a)  acc[a]     = fmaf(plw[a * 256 + c], vv, acc[a]);
#pragma unroll
                for (int a = 0; a < 12; ++a) acc[3 + a] = fmaf(pdw[a * 256 + c], vv, acc[3 + a]);
            }
        }
        float sc = -INFINITY;
#pragma unroll
        for (int a = 0; a < 3; ++a) {
            float lg = acc[a] + plb[a];
            out[plog_off(lv) + ((size_t)n * 3 + a) * HW + p] = lg;
            sc = fmaxf(sc, lg);
        }
        scores[soff_l(lv) + (size_t)n * HW + p] = sc;
#pragma unroll
        for (int a = 0; a < 12; ++a)
            out[pdel_off(lv) + ((size_t)n * 12 + a) * HW + p] = acc[3 + a] + pdb[a];
    } else {
        float acc[12];
#pragma unroll
        for (int a = 0; a < 12; ++a) acc[a] = 0.f;
        for (int ch = 0; ch < 16; ++ch) {
            size_t base = ioff + (((size_t)ch * HW + p) << 4);
            bf16x8 v0 = *(const bf16x8*)&h16o[base];
            bf16x8 v1 = *(const bf16x8*)&h16o[base + 8];
#pragma unroll
            for (int j = 0; j < 16; ++j) {
                float vv = (j < 8) ? (float)v0[j] : (float)v1[j - 8];
                int c = ch * 16 + j;
#pragma unroll
                for (int a = 0; a < 12; ++a) acc[a] = fmaf(odw[a * 256 + c], vv, acc[a]);
            }
        }
#pragma unroll
        for (int a = 0; a < 12; ++a)
            out[odel_off(lv) + ((size_t)n * 12 + a) * HW + p] = acc[a] + odb[a];
    }
}

// ---------------- per-level top-20 ------------------------------------------
__global__ __launch_bounds__(256) void topk_lvl_k(
    const float* __restrict__ scores, float* __restrict__ lv_sc,
    int* __restrict__ lv_ix)
{
    int l = blockIdx.x, n = blockIdx.y;
    int HW = 10240 >> (2 * l);
    const float* sp = scores + soff_l(l) + (size_t)n * HW;
    int tid = threadIdx.x;
    __shared__ float sc[10240];
    __shared__ float wv4[4];
    __shared__ int wi4[4];
    __shared__ int bcast;
    for (int i = tid; i < HW; i += 256) sc[i] = sp[i];
    __syncthreads();
    float bv = -INFINITY; int bi = 0x7fffffff;
    for (int i = tid; i < HW; i += 256)
        if (sc[i] > bv) { bv = sc[i]; bi = i; }
    const int w = tid >> 6, lane = tid & 63;
    for (int r = 0; r < 20; ++r) {
        float cv = bv; int ci = bi;
#pragma unroll
        for (int off = 32; off > 0; off >>= 1) {
            float ov = __shfl_xor(cv, off);
            int oi = __shfl_xor(ci, off);
            if (ov > cv || (ov == cv && oi < ci)) { cv = ov; ci = oi; }
        }
        if (lane == 0) { wv4[w] = cv; wi4[w] = ci; }
        __syncthreads();
        if (tid == 0) {
            float mv = wv4[0]; int mi = wi4[0];
#pragma unroll
            for (int j = 1; j < 4; ++j)
                if (wv4[j] > mv || (wv4[j] == mv && wi4[j] < mi)) { mv = wv4[j]; mi = wi4[j]; }
            bcast = mi;
            int idx = (n * 4 + l) * 20 + r;
            lv_sc[idx] = mv;
            lv_ix[idx] = mi;
        }
        __syncthreads();
        int mi = bcast;
        if ((mi & 255) == tid) {
            sc[mi] = -INFINITY;
            bv = -INFINITY; bi = 0x7fffffff;
            for (int i = tid; i < HW; i += 256)
                if (sc[i] > bv) { bv = sc[i]; bi = i; }
        }
    }
}

// ---------------- global select 20-of-80 + gather pf + pproj ----------------
__global__ __launch_bounds__(256) void sel_pproj_k(
    const float* __restrict__ lv_sc, const int* __restrict__ lv_ix,
    const __bf16* __restrict__ h16p, const float* __restrict__ WpT,
    const float* __restrict__ rn1b, float* __restrict__ pp)
{
    int n = blockIdx.x, tid = threadIdx.x;
    __shared__ int selL[20], selC[20];
    __shared__ float pfL[5120];
    __shared__ float wv2[2];
    __shared__ int wi2[2];
    __shared__ int bcast;
    float bv = -INFINITY; int bi = 0x7fffffff;
    if (tid < 80) { bv = lv_sc[n * 80 + tid]; bi = tid; }
    const int w = tid >> 6, lane = tid & 63;
    for (int r = 0; r < 20; ++r) {
        float cv = bv; int ci = bi;
#pragma unroll
        for (int off = 32; off > 0; off >>= 1) {
            float ov = __shfl_xor(cv, off);
            int oi = __shfl_xor(ci, off);
            if (ov > cv || (ov == cv && oi < ci)) { cv = ov; ci = oi; }
        }
        if (lane == 0 && w < 2) { wv2[w] = cv; wi2[w] = ci; }
        __syncthreads();
        if (tid == 0) {
            float mv = wv2[0]; int mi = wi2[0];
            if (wv2[1] > mv || (wv2[1] == mv && wi2[1] < mi)) { mv = wv2[1]; mi = wi2[1]; }
            bcast = mi;
            selL[r] = mi / 20;
            selC[r] = lv_ix[n * 80 + mi];
        }
        __syncthreads();
        if (bcast == bi) bv = -INFINITY;
    }
    for (int t = tid; t < 5120; t += 256) {
        int k = t >> 8, c = t & 255;
        int l = selL[k], cell = selC[k];
        int HW = 10240 >> (2 * l);
        pfL[k * 256 + c] =
            (float)h16p[loffE(l) + (size_t)n * HW * 256 +
                        (((size_t)(c >> 4) * HW + cell) << 4) + (c & 15)];
    }
    __syncthreads();
    float acc[20];
    float bb = rn1b[tid];
#pragma unroll
    for (int k = 0; k < 20; ++k) acc[k] = bb;
    for (int c = 0; c < 256; ++c) {
        float wv = WpT[c * 256 + tid];
#pragma unroll
        for (int k = 0; k < 20; ++k) acc[k] = fmaf(pfL[k * 256 + c], wv, acc[k]);
    }
#pragma unroll
    for (int k = 0; k < 20; ++k)
        pp[(size_t)n * 5120 + k * 256 + tid] = acc[k];
}

// ---------------- fused o_proj + hsum + rn2 + MFMA-ol -----------------------
__global__ __launch_bounds__(256) void orel_k(
    const __bf16* __restrict__ H16o, const __bf16* __restrict__ Wo16,
    const __bf16* __restrict__ rn216, const __bf16* __restrict__ olw32,
    const float* __restrict__ pp, const float* __restrict__ rn2b,
    const float* __restrict__ olb, float* __restrict__ out)
{
    __shared__ __bf16 hb[16 * 64 * 24];
    __shared__ __bf16 pp16[5120];
    __shared__ float red[768];
    const int tid = threadIdx.x;
    const int n = blockIdx.y;
    int bx = blockIdx.x;
    int lv = (bx < 160) ? 0 : (bx < 200) ? 1 : (bx < 210) ? 2 : 3;
    int tb = (lv == 0) ? 0 : (lv == 1) ? 160 : (lv == 2) ? 200 : 210;
    int HW = 10240 >> (2 * lv);
    size_t yoff = loffE(lv) + (size_t)n * HW * 256;
    int p0 = (bx - tb) << 6;
    int npix = min(64, HW - p0);

    {
        const float* ps = pp + (size_t)n * 5120;
        for (int i = tid; i < 1280; i += 256) {
            float4 f = *(const float4*)&ps[i * 4];
            U8 v;
            v.h[0] = (__bf16)f.x; v.h[1] = (__bf16)f.y;
            v.h[2] = (__bf16)f.z; v.h[3] = (__bf16)f.w;
            *(unsigned long long*)&pp16[i * 4] = v.u;
        }
    }
    __syncthreads();

    const int w = tid >> 6, l64 = tid & 63;
    const int lane = l64 & 31, half = l64 >> 5;
    const int dbase = w << 6;

    f32x16 acc00 = {}, acc01 = {}, acc10 = {}, acc11 = {};
    for (int c16 = 0; c16 < 16; ++c16) {
        bf16x8 a0 = *(const bf16x8*)&Wo16[(((c16 << 8) + dbase + lane) << 4) + (half << 3)];
        bf16x8 a1 = *(const bf16x8*)&Wo16[(((c16 << 8) + dbase + 32 + lane) << 4) + (half << 3)];
        bf16x8 b0 = *(const bf16x8*)&H16o[yoff + (((size_t)c16 * HW + p0 + lane) << 4) + (half << 3)];
        bf16x8 b1 = *(const bf16x8*)&H16o[yoff + (((size_t)c16 * HW + p0 + 32 + lane) << 4) + (half << 3)];
        acc00 = __builtin_amdgcn_mfma_f32_32x32x16_bf16(a0, b0, acc00, 0, 0, 0);
        acc01 = __builtin_amdgcn_mfma_f32_32x32x16_bf16(a0, b1, acc01, 0, 0, 0);
        acc10 = __builtin_amdgcn_mfma_f32_32x32x16_bf16(a1, b0, acc10, 0, 0, 0);
        acc11 = __builtin_amdgcn_mfma_f32_32x32x16_bf16(a1, b1, acc11, 0, 0, 0);
    }
#pragma unroll
    for (int b = 0; b < 2; ++b) {
        const f32x16& A0 = b ? acc10 : acc00;
        const f32x16& A1 = b ? acc11 : acc01;
#pragma unroll
        for (int q = 0; q < 4; ++q) {
            int d0 = dbase + b * 32 + q * 8 + half * 4;
            float h0[4] = {0.f, 0.f, 0.f, 0.f}, h1[4] = {0.f, 0.f, 0.f, 0.f};
            for (int k = 0; k < 20; ++k) {
                U8 pk;
                pk.u = *(const unsigned long long*)&pp16[k * 256 + d0];
#pragma unroll
                for (int j = 0; j < 4; ++j) {
                    float pkv = (float)pk.h[j];
                    h0[j] += fmaxf(A0[q * 4 + j] + pkv, 0.f);
                    h1[j] += fmaxf(A1[q * 4 + j] + pkv, 0.f);
                }
            }
            U8 v0, v1;
#pragma unroll
            for (int j = 0; j < 4; ++j) { v0.h[j] = (__bf16)h0[j]; v1.h[j] = (__bf16)h1[j]; }
            *(unsigned long long*)&hb[((d0 >> 4) * 64 + lane) * 24 + (d0 & 15)] = v0.u;
            *(unsigned long long*)&hb[((d0 >> 4) * 64 + 32 + lane) * 24 + (d0 & 15)] = v1.u;
        }
    }
    __syncthreads();
    f32x16 e00 = {}, e01 = {}, e10 = {}, e11 = {};
    for (int d16 = 0; d16 < 16; ++d16) {
        bf16x8 a0 = *(const bf16x8*)&rn216[(((d16 << 8) + dbase + lane) << 4) + (half << 3)];
        bf16x8 a1 = *(const bf16x8*)&rn216[(((d16 << 8) + dbase + 32 + lane) << 4) + (half << 3)];
        bf16x8 b0 = *(const bf16x8*)&hb[(d16 * 64 + lane) * 24 + (half << 3)];
        bf16x8 b1 = *(const bf16x8*)&hb[(d16 * 64 + 32 + lane) * 24 + (half << 3)];
        e00 = __builtin_amdgcn_mfma_f32_32x32x16_bf16(a0, b0, e00, 0, 0, 0);
        e01 = __builtin_amdgcn_mfma_f32_32x32x16_bf16(a0, b1, e01, 0, 0, 0);
        e10 = __builtin_amdgcn_mfma_f32_32x32x16_bf16(a1, b0, e10, 0, 0, 0);
        e11 = __builtin_amdgcn_mfma_f32_32x32x16_bf16(a1, b1, e11, 0, 0, 0);
    }
    __syncthreads();
#pragma unroll
    for (int b = 0; b < 2; ++b) {
        const f32x16& A0 = b ? e10 : e00;
        const f32x16& A1 = b ? e11 : e01;
#pragma unroll
        for (int q = 0; q < 4; ++q) {
            int e0 = dbase + b * 32 + q * 8 + half * 4;
            float4 bb = *(const float4*)&rn2b[e0];
            U8 v0, v1;
            v0.h[0] = (__bf16)fmaxf(A0[q * 4 + 0] + bb.x, 0.f);
            v0.h[1] = (__bf16)fmaxf(A0[q * 4 + 1] + bb.y, 0.f);
            v0.h[2] = (__bf16)fmaxf(A0[q * 4 + 2] + bb.z, 0.f);
            v0.h[3] = (__bf16)fmaxf(A0[q * 4 + 3] + bb.w, 0.f);
            v1.h[0] = (__bf16)fmaxf(A1[q * 4 + 0] + bb.x, 0.f);
            v1.h[1] = (__bf16)fmaxf(A1[q * 4 + 1] + bb.y, 0.f);
            v1.h[2] = (__bf16)fmaxf(A1[q * 4 + 2] + bb.z, 0.f);
            v1.h[3] = (__bf16)fmaxf(A1[q * 4 + 3] + bb.w, 0.f);
            *(unsigned long long*)&hb[((e0 >> 4) * 64 + lane) * 24 + (e0 & 15)] = v0.u;
            *(unsigned long long*)&hb[((e0 >> 4) * 64 + 32 + lane) * 24 + (e0 & 15)] = v1.u;
        }
    }
    __syncthreads();
    f32x16 ol0 = {}, ol1 = {};
#pragma unroll
    for (int j = 0; j < 4; ++j) {
        int e16 = w * 4 + j;
        bf16x8 a = *(const bf16x8*)&olw32[e16 * 512 + lane * 16 + (half << 3)];
        bf16x8 b0 = *(const bf16x8*)&hb[(e16 * 64 + lane) * 24 + (half << 3)];
        bf16x8 b1 = *(const bf16x8*)&hb[(e16 * 64 + 32 + lane) * 24 + (half << 3)];
        ol0 = __builtin_amdgcn_mfma_f32_32x32x16_bf16(a, b0, ol0, 0, 0, 0);
        ol1 = __builtin_amdgcn_mfma_f32_32x32x16_bf16(a, b1, ol1, 0, 0, 0);
    }
    if (half == 0) {
#pragma unroll
        for (int r = 0; r < 3; ++r) {
            red[(r * 64 + lane) * 4 + w] = ol0[r];
            red[(r * 64 + lane + 32) * 4 + w] = ol1[r];
        }
    }
    __syncthreads();
    if (tid < 192) {
        int a = tid >> 6, px = tid & 63;
        if (px < npix) {
            float4 p4 = *(const float4*)&red[(a * 64 + px) * 4];
            out[olog_off(lv) + ((size_t)n * 3 + a) * HW + p0 + px] =
                olb[a] + p4.x + p4.y + p4.z + p4.w;
        }
    }
}

extern "C" void kernel_launch(void* const* d_in, const int* in_sizes, int n_in,
                              void* d_out, int out_size, void* d_ws, size_t ws_size,
                              hipStream_t stream)
{
    const float* feat[4] = {(const float*)d_in[0], (const float*)d_in[1],
                            (const float*)d_in[2], (const float*)d_in[3]};
    const float* pc1w = (const float*)d_in[4];  const float* pc1b = (const float*)d_in[5];
    const float* pc2w = (const float*)d_in[6];  const float* pc2b = (const float*)d_in[7];
    const float* oc1w = (const float*)d_in[8];  const float* oc1b = (const float*)d_in[9];
    const float* oc2w = (const float*)d_in[10]; const float* oc2b = (const float*)d_in[11];
    const float* rn1w = (const float*)d_in[12]; const float* rn1b = (const float*)d_in[13];
    const float* rn2w = (const float*)d_in[14]; const float* rn2b = (const float*)d_in[15];
    const float* plw  = (const float*)d_in[16]; const float* plb  = (const float*)d_in[17];
    const float* pdw  = (const float*)d_in[18]; const float* pdb  = (const float*)d_in[19];
    const float* olw  = (const float*)d_in[20]; const float* olb  = (const float*)d_in[21];
    const float* odw  = (const float*)d_in[22]; const float* odb  = (const float*)d_in[23];

    float* ws = (float*)d_ws;
    __bf16* bufA = (__bf16*)(ws);             // X16 -> H16p
    __bf16* bufB = (__bf16*)(ws + 3481600);   // Y16p -> (fallback) H16o
    __bf16* bufC = (__bf16*)(ws + 6963200);   // Y16o
    __bf16* wtap = (__bf16*)(ws + 10444800);  // 4 x 589824 bf16
    __bf16* wt_pc1 = wtap;
    __bf16* wt_pc2 = wtap + 589824;
    __bf16* wt_oc1 = wtap + 2 * 589824;
    __bf16* wt_oc2 = wtap + 3 * 589824;
    __bf16* Wo16  = (__bf16*)(ws + 11624448);
    __bf16* rn216 = (__bf16*)(ws + 11657216);
    float* WpT    = ws + 11689984;
    float* scores = ws + 11755520;
    float* lv_sc  = ws + 11783040;
    int*   lv_ix  = (int*)(ws + 11783200);
    __bf16* olw32 = (__bf16*)(ws + 11783360);   // 8192 bf16
    float* pp     = ws + 11793280;
    __bf16* zrow  = (__bf16*)(ws + 11803520);
    __bf16* bufD  = (__bf16*)(ws + 11803904);   // optional H16o (merged path)
    float* out    = (float*)d_out;

    const bool merged = ws_size >= (size_t)(11803904 + 3481600) * 4;

    hipLaunchKernelGGL(prep_all_k, dim3(3024), dim3(256), 0, stream,
                       feat[0], feat[1], feat[2], feat[3],
                       pc1w, pc2w, oc1w, oc2w, rn1w, rn2w, olw,
                       wtap, WpT, Wo16, rn216, olw32, (unsigned*)zrow, bufA);

    // conv1 (mode 0, XCD-swizzled): p -> bufB, o -> bufC
    hipLaunchKernelGGL(conv3x3_v6, dim3(896), dim3(256), 0, stream,
                       bufA, bufA, wt_pc1, wt_oc1, pc1b, oc1b, zrow,
                       bufB, bufC, 0);

    __bf16* h16o;
    if (merged) {
        hipLaunchKernelGGL(conv3x3_v6, dim3(864), dim3(256), 0, stream,
                           bufB, bufC, wt_pc2, wt_oc2, pc2b, oc2b, zrow,
                           bufA, bufD, 1);
        h16o = bufD;
    } else {
        hipLaunchKernelGGL(conv3x3_v6, dim3(448), dim3(256), 0, stream,
                           bufB, bufB, wt_pc2, wt_pc2, pc2b, pc2b, zrow,
                           bufA, bufA, 2);
        hipLaunchKernelGGL(conv3x3_v6, dim3(448), dim3(256), 0, stream,
                           bufC, bufC, wt_oc2, wt_oc2, oc2b, oc2b, zrow,
                           bufB, bufB, 2);
        h16o = bufB;
    }

    hipLaunchKernelGGL(heads_k, dim3(54, 2, 2), dim3(256), 0, stream,
                       bufA, h16o, plw, plb, pdw, pdb, odw, odb, out, scores);

    hipLaunchKernelGGL(topk_lvl_k, dim3(4, 2), dim3(256), 0, stream,
                       scores, lv_sc, lv_ix);
    hipLaunchKernelGGL(sel_pproj_k, dim3(2), dim3(256), 0, stream,
                       lv_sc, lv_ix, bufA, WpT, rn1b, pp);

    hipLaunchKernelGGL(orel_k, dim3(213, 2), dim3(256), 0, stream,
                       h16o, Wo16, rn216, olw32, pp, rn2b, olb, out);
}